// Round 13
// baseline (431.194 us; speedup 1.0000x reference)
//
#include <hip/hip_runtime.h>

#define NB   32
#define NN   100000
#define NE   1000000
#define HD   64
#define AD   5
#define NL   3
#define NRL  231      // N_REL + 1
#define NTM  365
#define NOUT 228096   // 32 * 7128
#define NBLK1 391     // ceil(NN/256)
#define BLKN 32       // nodes per reduce block (NN = 3125 * 32 exactly)
#define NBLK2 3125    // NN / BLKN

// meta packing: w0 = src | (rel<<17) | (cls<<25) ; w1 = ta | (q<<9)

// bf16 helpers (hidden stored as bf16 to halve gather traffic)
__device__ __forceinline__ float bflo(unsigned u) { return __uint_as_float(u << 16); }
__device__ __forceinline__ float bfhi(unsigned u) { return __uint_as_float(u & 0xffff0000u); }
__device__ __forceinline__ unsigned packbf2(float x, float y) {
    unsigned ux = __float_as_uint(x), uy = __float_as_uint(y);
    ux = (ux + 0x7fffu + ((ux >> 16) & 1u)) >> 16;
    uy = (uy + 0x7fffu + ((uy >> 16) & 1u)) >> 16;
    return ux | (uy << 16);
}

using vbf8  = __attribute__((ext_vector_type(8))) short;   // 8 bf16 (4 VGPRs) MFMA A/B frag
using f32x4 = __attribute__((ext_vector_type(4))) float;   // MFMA C/D frag

// ---------------------------------------------------------------------------
// WTB: W in bf16 split (hi/lo) laid out as MFMA B-fragments.
// flat idx = ((((c*2 + hl)*2 + ks)*4 + nt)*64 + lane)*8 ushorts
// value(lane, j) = W_c[h = nt*16 + (lane&15)][k = ks*32 + (lane>>4)*8 + j]
// c: 0=Wf(pos) 1=Wn(zero) 2=Wp(neg); hl: 0=hi 1=residual
__global__ __launch_bounds__(256) void prep_wtb_kernel(
    const float* __restrict__ Wp, const float* __restrict__ Wn,
    const float* __restrict__ Wf, ushort* __restrict__ WTB)
{
    int i = blockIdx.x * 256 + threadIdx.x;
    if (i >= 3072) return;
    int lane = i & 63;
    int nt = (i >> 6) & 3;
    int ks = (i >> 8) & 1;
    int hl = (i >> 9) & 1;
    int c  = i >> 10;
    const float* W = (c == 0) ? Wf : (c == 1 ? Wn : Wp);
    int h  = nt * 16 + (lane & 15);
    int k0 = ks * 32 + (lane >> 4) * 8;
    unsigned up[4];
    #pragma unroll
    for (int j = 0; j < 4; ++j) {
        float x = W[h * 64 + k0 + 2 * j];
        float y = W[h * 64 + k0 + 2 * j + 1];
        unsigned pb = packbf2(x, y);
        if (hl) {
            float rx = x - bflo(pb);
            float ry = y - bfhi(pb);
            pb = packbf2(rx, ry);
        }
        up[j] = pb;
    }
    *(uint4*)(WTB + (size_t)i * 8) = make_uint4(up[0], up[1], up[2], up[3]);
}

// ---------------------------------------------------------------------------
// bf16 copies of rela (all 3 layer slices) and temb for the edge-gather phase.
__global__ __launch_bounds__(256) void prep_tb_kernel(
    const float* __restrict__ rela_embed,  // [3][231][64]
    const float* __restrict__ time_embed,  // [365][64]
    ushort* __restrict__ relb,             // [3][231][64] bf16
    ushort* __restrict__ tembb)            // [365][64] bf16
{
    const int nrel_w = 3 * NRL * HD / 2;   // 22176 packed words
    const int ntmb_w = NTM * HD / 2;       // 11680
    int i = blockIdx.x * 256 + threadIdx.x;
    if (i < nrel_w) {
        ((unsigned*)relb)[i] = packbf2(rela_embed[2 * i], rela_embed[2 * i + 1]);
    } else if (i < nrel_w + ntmb_w) {
        int k = i - nrel_w;
        ((unsigned*)tembb)[k] = packbf2(time_embed[2 * k], time_embed[2 * k + 1]);
    }
}

// ---------------------------------------------------------------------------
__global__ __launch_bounds__(256) void prep_tables_kernel(
    const float* __restrict__ rela_embed,   // [3][231][64]
    const float* __restrict__ W1,           // [3][5][192]
    float* __restrict__ Trel,               // [3][231][8]
    float* __restrict__ Tq)                 // [3][231][8]
{
    int l = blockIdx.x;
    int r = threadIdx.x;
    if (r >= NRL) return;
    const float4* rrow = (const float4*)(rela_embed + ((size_t)l * NRL + r) * HD);
    const float* W1l = W1 + (size_t)l * AD * 192;
    float tr[AD] = {0,0,0,0,0}, tq[AD] = {0,0,0,0,0};
    #pragma unroll
    for (int k4 = 0; k4 < 16; ++k4) {
        float4 x = rrow[k4];
        #pragma unroll
        for (int a = 0; a < AD; ++a) {
            const float* wr = W1l + a * 192 + 64 + k4 * 4;
            const float* wq = W1l + a * 192 + 128 + k4 * 4;
            tr[a] = fmaf(x.x, wr[0], tr[a]); tr[a] = fmaf(x.y, wr[1], tr[a]);
            tr[a] = fmaf(x.z, wr[2], tr[a]); tr[a] = fmaf(x.w, wr[3], tr[a]);
            tq[a] = fmaf(x.x, wq[0], tq[a]); tq[a] = fmaf(x.y, wq[1], tq[a]);
            tq[a] = fmaf(x.z, wq[2], tq[a]); tq[a] = fmaf(x.w, wq[3], tq[a]);
        }
    }
    float* tro = Trel + ((size_t)l * NRL + r) * 8;
    float* tqo = Tq   + ((size_t)l * NRL + r) * 8;
    #pragma unroll
    for (int a = 0; a < AD; ++a) { tro[a] = tr[a]; tqo[a] = tq[a]; }
    tro[5] = tro[6] = tro[7] = 0.f;
    tqo[5] = tqo[6] = tqo[7] = 0.f;
}

// ---------------------------------------------------------------------------
// Counting sort by dst. hist captures each edge's rank within its dst bucket
// (atomicAdd return, fire-and-forget); the scatter then needs NO atomic (R5).
__global__ __launch_bounds__(256) void hist_kernel(
    const int* __restrict__ dst_idx, int* __restrict__ deg,
    ushort* __restrict__ rank)
{
    int e = blockIdx.x * 256 + threadIdx.x;
    if (e < NE) rank[e] = (ushort)atomicAdd(&deg[dst_idx[e]], 1);
}

__global__ __launch_bounds__(256) void scan1_kernel(
    const int* __restrict__ deg, int* __restrict__ tmp, int* __restrict__ bsum)
{
    __shared__ int s[256];
    int tid = threadIdx.x;
    int i = blockIdx.x * 256 + tid;
    int v = (i < NN) ? deg[i] : 0;
    s[tid] = v;
    __syncthreads();
    #pragma unroll
    for (int st = 1; st < 256; st <<= 1) {
        int t = (tid >= st) ? s[tid - st] : 0;
        __syncthreads();
        s[tid] += t;
        __syncthreads();
    }
    if (i < NN) tmp[i] = s[tid];
    if (tid == 255) bsum[blockIdx.x] = s[255];
}

__global__ __launch_bounds__(512) void scan2_kernel(
    const int* __restrict__ bsum, int* __restrict__ bpref)
{
    __shared__ int s[512];
    int tid = threadIdx.x;
    int v = (tid < NBLK1) ? bsum[tid] : 0;
    s[tid] = v;
    __syncthreads();
    #pragma unroll
    for (int st = 1; st < 512; st <<= 1) {
        int t = (tid >= st) ? s[tid - st] : 0;
        __syncthreads();
        s[tid] += t;
        __syncthreads();
    }
    if (tid < NBLK1) bpref[tid] = s[tid] - v;  // exclusive
}

__global__ __launch_bounds__(256) void scan3_kernel(
    const int* __restrict__ deg, const int* __restrict__ tmp,
    const int* __restrict__ bpref, int* __restrict__ off)
{
    int i = blockIdx.x * 256 + threadIdx.x;
    if (i >= NN) return;
    int incl = tmp[i] + bpref[i >> 8];
    off[i + 1] = incl;
    if (i == 0) off[0] = 0;
}

// scatter into dst-sorted order, ATOMIC-FREE: pos = off[d] + rank[e].
// R8 form: layer-0 score scatter rides along (random stores are
// fire-and-forget — R3 lesson).
__global__ __launch_bounds__(256) void sort_scatter_kernel(
    const int* __restrict__ dst_idx, const int* __restrict__ src_idx,
    const int* __restrict__ rel_idx, const int* __restrict__ rel_time,
    const int* __restrict__ batch_idx, const int* __restrict__ query_rel,
    const int* __restrict__ off, const ushort* __restrict__ rank,
    const float* __restrict__ Trel0, const float* __restrict__ Tq0,
    const float* __restrict__ W2,
    int2* __restrict__ meta, float* __restrict__ score0)
{
    int e = blockIdx.x * 256 + threadIdx.x;
    if (e >= NE) return;
    int d = dst_idx[e];
    int rt = rel_time[e];
    int cls = (rt > 0) ? 0 : ((rt == 0) ? 1 : 2);
    int ta = (rt < 0) ? -rt : rt;
    int rel = rel_idx[e];
    int q = query_rel[batch_idx[e]];
    int pos = off[d] + (int)rank[e];
    int2 m;
    m.x = src_idx[e] | (rel << 17) | (cls << 25);
    m.y = ta | (q << 9);
    meta[pos] = m;

    float4 t0 = *(const float4*)(Trel0 + rel * 8);
    float  t4 = Trel0[rel * 8 + 4];
    float4 u0 = *(const float4*)(Tq0 + q * 8);
    float  u4 = Tq0[q * 8 + 4];
    float z = 0.f;
    z = fmaf(fmaxf(t0.x + u0.x, 0.f), W2[0], z);
    z = fmaf(fmaxf(t0.y + u0.y, 0.f), W2[1], z);
    z = fmaf(fmaxf(t0.z + u0.z, 0.f), W2[2], z);
    z = fmaf(fmaxf(t0.w + u0.w, 0.f), W2[3], z);
    z = fmaf(fmaxf(t4   + u4,   0.f), W2[4], z);
    score0[pos] = 1.f / (1.f + __expf(-z));
}

// ---------------------------------------------------------------------------
// Standalone score for L1/L2 (NE-parallel: TLP hides the proj gather — the
// R10 lesson is that this gather must NOT live inside the segment loop).
__global__ __launch_bounds__(256) void score_kernel(
    const float* __restrict__ proj,     // [NN][8]
    const float* __restrict__ Trel,
    const float* __restrict__ Tq,
    const float* __restrict__ W2,
    const int2* __restrict__ meta,
    float* __restrict__ score)
{
    int j = blockIdx.x * 256 + threadIdx.x;
    if (j >= NE) return;
    int2 mt = meta[j];
    int rel = (mt.x >> 17) & 0xFF;
    int q   = (mt.y >> 9) & 0xFF;
    int src = mt.x & 0x1FFFF;

    float4 t0 = *(const float4*)(Trel + rel * 8);
    float  t4 = Trel[rel * 8 + 4];
    float4 u0 = *(const float4*)(Tq + q * 8);
    float  u4 = Tq[q * 8 + 4];
    float4 p0 = *(const float4*)(proj + (size_t)src * 8);
    float  p4 = proj[(size_t)src * 8 + 4];
    float z = 0.f;
    z = fmaf(fmaxf(p0.x + t0.x + u0.x, 0.f), W2[0], z);
    z = fmaf(fmaxf(p0.y + t0.y + u0.y, 0.f), W2[1], z);
    z = fmaf(fmaxf(p0.z + t0.z + u0.z, 0.f), W2[2], z);
    z = fmaf(fmaxf(p0.w + t0.w + u0.w, 0.f), W2[3], z);
    z = fmaf(fmaxf(p4   + t4   + u4,   0.f), W2[4], z);
    score[j] = 1.f / (1.f + __expf(-z));
}

// ---------------------------------------------------------------------------
// Accumulate one edge from preloaded bf16 rows (rv=rela, tv=temb, hv=hidden).
// A[6] = [cls0 h0..3, cls0 h4..7, cls1 lo, cls1 hi, cls2 lo, cls2 hi]
template <bool HZ>
__device__ __forceinline__ void edge_acc(
    int mx, float sc, uint4 rv, uint4 tv, uint4 hv, float4* __restrict__ A)
{
    int cl = (mx >> 25) & 3;
    float4 v0, v1;
    v0.x = bflo(rv.x) + bflo(tv.x); v0.y = bfhi(rv.x) + bfhi(tv.x);
    v0.z = bflo(rv.y) + bflo(tv.y); v0.w = bfhi(rv.y) + bfhi(tv.y);
    v1.x = bflo(rv.z) + bflo(tv.z); v1.y = bfhi(rv.z) + bfhi(tv.z);
    v1.z = bflo(rv.w) + bflo(tv.w); v1.w = bfhi(rv.w) + bfhi(tv.w);
    if (!HZ) {
        v0.x += bflo(hv.x); v0.y += bfhi(hv.x);
        v0.z += bflo(hv.y); v0.w += bfhi(hv.y);
        v1.x += bflo(hv.z); v1.y += bfhi(hv.z);
        v1.z += bflo(hv.w); v1.w += bfhi(hv.w);
    }
    float sA = (cl == 0) ? sc : 0.f;
    float sB = (cl == 1) ? sc : 0.f;
    float sC = (cl == 2) ? sc : 0.f;
    A[0].x = fmaf(sA, v0.x, A[0].x); A[0].y = fmaf(sA, v0.y, A[0].y);
    A[0].z = fmaf(sA, v0.z, A[0].z); A[0].w = fmaf(sA, v0.w, A[0].w);
    A[1].x = fmaf(sA, v1.x, A[1].x); A[1].y = fmaf(sA, v1.y, A[1].y);
    A[1].z = fmaf(sA, v1.z, A[1].z); A[1].w = fmaf(sA, v1.w, A[1].w);
    A[2].x = fmaf(sB, v0.x, A[2].x); A[2].y = fmaf(sB, v0.y, A[2].y);
    A[2].z = fmaf(sB, v0.z, A[2].z); A[2].w = fmaf(sB, v0.w, A[2].w);
    A[3].x = fmaf(sB, v1.x, A[3].x); A[3].y = fmaf(sB, v1.y, A[3].y);
    A[3].z = fmaf(sB, v1.z, A[3].z); A[3].w = fmaf(sB, v1.w, A[3].w);
    A[4].x = fmaf(sC, v0.x, A[4].x); A[4].y = fmaf(sC, v0.y, A[4].y);
    A[4].z = fmaf(sC, v0.z, A[4].z); A[4].w = fmaf(sC, v0.w, A[4].w);
    A[5].x = fmaf(sC, v1.x, A[5].x); A[5].y = fmaf(sC, v1.y, A[5].y);
    A[5].z = fmaf(sC, v1.z, A[5].z); A[5].w = fmaf(sC, v1.w, A[5].w);
}

__device__ __forceinline__ uint4 ldrow(const ushort* __restrict__ base, int row, int hc8)
{
    return *(const uint4*)(base + (size_t)row * HD + hc8);
}

// 4-edge register batch — all member accesses are static, so this lives
// entirely in VGPRs (rule: no runtime indexing).
struct EB {
    int2 m0, m1, m2, m3;
    float s0, s1, s2, s3;
    uint4 r0, r1, r2, r3, t0, t1, t2, t3, h0, h1, h2, h3;
};

template <bool HZ>
__device__ __forceinline__ void load_batch(
    EB& b, int j, const int2* __restrict__ meta, const float* __restrict__ score,
    const ushort* __restrict__ relb, const ushort* __restrict__ tembb,
    const ushort* __restrict__ hidden_in, int hc8)
{
    b.m0 = meta[j];     b.m1 = meta[j + 1];
    b.m2 = meta[j + 2]; b.m3 = meta[j + 3];
    b.s0 = score[j];     b.s1 = score[j + 1];
    b.s2 = score[j + 2]; b.s3 = score[j + 3];
    b.r0 = ldrow(relb, (b.m0.x >> 17) & 0xFF, hc8);
    b.r1 = ldrow(relb, (b.m1.x >> 17) & 0xFF, hc8);
    b.r2 = ldrow(relb, (b.m2.x >> 17) & 0xFF, hc8);
    b.r3 = ldrow(relb, (b.m3.x >> 17) & 0xFF, hc8);
    b.t0 = ldrow(tembb, b.m0.y & 511, hc8);
    b.t1 = ldrow(tembb, b.m1.y & 511, hc8);
    b.t2 = ldrow(tembb, b.m2.y & 511, hc8);
    b.t3 = ldrow(tembb, b.m3.y & 511, hc8);
    if (!HZ) {
        b.h0 = ldrow(hidden_in, b.m0.x & 0x1FFFF, hc8);
        b.h1 = ldrow(hidden_in, b.m1.x & 0x1FFFF, hc8);
        b.h2 = ldrow(hidden_in, b.m2.x & 0x1FFFF, hc8);
        b.h3 = ldrow(hidden_in, b.m3.x & 0x1FFFF, hc8);
    }
}

template <bool HZ>
__device__ __forceinline__ void proc_batch(EB& b, float4* __restrict__ a)
{
    const uint4 zz = make_uint4(0, 0, 0, 0);
    edge_acc<HZ>(b.m0.x, b.s0, b.r0, b.t0, HZ ? zz : b.h0, a);
    edge_acc<HZ>(b.m1.x, b.s1, b.r1, b.t1, HZ ? zz : b.h1, a);
    edge_acc<HZ>(b.m2.x, b.s2, b.r2, b.t2, HZ ? zz : b.h2, a);
    edge_acc<HZ>(b.m3.x, b.s3, b.r3, b.t3, HZ ? zz : b.h3, a);
}

// ---------------------------------------------------------------------------
// Fused segmented-reduce + MFMA transform + proj/out epilogue.
// R6: 32-node tile, one node per 8-lane group. R7/R8: bf16 tables.
// R11: OUT variant fuses the final Wc-dot. R13: explicit 2-deep software
// pipeline over 4-edge batches — batch B's 12 row-gathers are ISSUED before
// batch A's ~340 VALU ops run, alternating A/B, so each gather has a full
// accumulate phase between issue and use. (R12 showed the compiler won't do
// this on its own: it sinks loads next to uses regardless of VGPR budget.)
#define SPITCH 68
template <bool HZ, bool PROJ, bool OUT>
__global__ __launch_bounds__(256, 2) void reduce_transform_kernel(
    const ushort* __restrict__ hidden_in,   // bf16 [NN][64]
    const ushort* __restrict__ relb,        // layer slice [231][64] bf16
    const ushort* __restrict__ tembb,       // [365][64] bf16
    const float* __restrict__ score,        // [E] sorted
    const int2* __restrict__ meta,          // [E] sorted
    const int*  __restrict__ off,           // [NN+1]
    const ushort* __restrict__ WTB,         // bf16 split W frags [3][2][2][4][64][8]
    const float* __restrict__ W1next,       // next layer slice [5][192] (if PROJ)
    ushort* __restrict__ hidden_out,        // bf16 [NN][64] (if !OUT)
    float* __restrict__ proj_out,           // [NN][8] (if PROJ)
    const float* __restrict__ Wc,           // [64] (if OUT)
    const float* __restrict__ bc,           // [1] (if OUT)
    float* __restrict__ outv)               // [NOUT] (if OUT)
{
    __shared__ float lds_t[BLKN * SPITCH];   // 8704 B
    int tid  = threadIdx.x;
    int lane = tid & 63;
    int w    = __builtin_amdgcn_readfirstlane(tid >> 6);  // 0..3
    int gid  = tid >> 3;                                   // 0..31 (node group)
    int hc   = tid & 7;                                    // 0..7
    int hc8  = hc * 8;
    int node0 = blockIdx.x * BLKN;
    int node  = node0 + gid;                               // NN = 3125*32: always valid

    float4 a[6];
    #pragma unroll
    for (int c = 0; c < 6; ++c)
        a[c] = make_float4(0.f, 0.f, 0.f, 0.f);

    {
        int o0 = off[node];
        int o1 = off[node + 1];
        int j = o0;
        EB A, B;
        bool haveA = (j + 4 <= o1);
        if (haveA) { load_batch<HZ>(A, j, meta, score, relb, tembb, hidden_in, hc8); j += 4; }
        while (haveA) {
            bool haveB = (j + 4 <= o1);
            if (haveB) { load_batch<HZ>(B, j, meta, score, relb, tembb, hidden_in, hc8); j += 4; }
            proc_batch<HZ>(A, a);
            if (!haveB) break;
            haveA = (j + 4 <= o1);
            if (haveA) { load_batch<HZ>(A, j, meta, score, relb, tembb, hidden_in, hc8); j += 4; }
            proc_batch<HZ>(B, a);
        }
        const uint4 zz = make_uint4(0, 0, 0, 0);
        for (; j < o1; ++j) {
            int2 m0 = meta[j];
            float s0 = score[j];
            uint4 r0 = ldrow(relb, (m0.x >> 17) & 0xFF, hc8);
            uint4 t0 = ldrow(tembb, m0.y & 511, hc8);
            uint4 h0 = zz;
            if (!HZ) h0 = ldrow(hidden_in, m0.x & 0x1FFFF, hc8);
            edge_acc<HZ>(m0.x, s0, r0, t0, h0, a);
        }
    }

    // --- transform via split-bf16 MFMA, one class slab at a time ---
    unsigned* lds_u = (unsigned*)lds_t;
    int rl = lane & 15;
    int t  = lane >> 4;
    int rt = w & 1;    // row-tile (nodes rt*16..rt*16+15)
    int ct = w >> 1;   // col-pair (nt = 2ct, 2ct+1)
    f32x4 accd[2];
    accd[0] = (f32x4){0.f, 0.f, 0.f, 0.f};
    accd[1] = (f32x4){0.f, 0.f, 0.f, 0.f};

    #pragma unroll
    for (int c = 0; c < 3; ++c) {
        __syncthreads();   // protect previous slab's reads
        {
            float4 v0 = a[2 * c];
            float4 v1 = a[2 * c + 1];
            unsigned p0 = packbf2(v0.x, v0.y);
            unsigned p1 = packbf2(v0.z, v0.w);
            unsigned p2 = packbf2(v1.x, v1.y);
            unsigned p3 = packbf2(v1.z, v1.w);
            unsigned q0 = packbf2(v0.x - bflo(p0), v0.y - bfhi(p0));
            unsigned q1 = packbf2(v0.z - bflo(p1), v0.w - bfhi(p1));
            unsigned q2 = packbf2(v1.x - bflo(p2), v1.y - bfhi(p2));
            unsigned q3 = packbf2(v1.z - bflo(p3), v1.w - bfhi(p3));
            *(uint4*)(lds_u + gid * SPITCH + hc * 4)      = make_uint4(p0, p1, p2, p3);
            *(uint4*)(lds_u + gid * SPITCH + 32 + hc * 4) = make_uint4(q0, q1, q2, q3);
        }
        __syncthreads();
        #pragma unroll
        for (int ks = 0; ks < 2; ++ks) {
            const unsigned* rowp = lds_u + (rt * 16 + rl) * SPITCH + ks * 16 + t * 4;
            vbf8 ah = *(const vbf8*)rowp;
            vbf8 al = *(const vbf8*)(rowp + 32);
            #pragma unroll
            for (int b = 0; b < 2; ++b) {
                int nt = ct * 2 + b;
                const ushort* bp = WTB +
                    (size_t)((((c * 2) * 2 + ks) * 4 + nt) * 64 + lane) * 8;
                vbf8 bh = *(const vbf8*)bp;
                vbf8 bl = *(const vbf8*)(bp + 4096);   // hl=1 plane
                accd[b] = __builtin_amdgcn_mfma_f32_16x16x32_bf16(ah, bh, accd[b], 0, 0, 0);
                accd[b] = __builtin_amdgcn_mfma_f32_16x16x32_bf16(al, bh, accd[b], 0, 0, 0);
                accd[b] = __builtin_amdgcn_mfma_f32_16x16x32_bf16(ah, bl, accd[b], 0, 0, 0);
            }
        }
    }

    // D frag (col=lane&15, row=(lane>>4)*4+i) -> LDS [node][h] fp32
    __syncthreads();
    #pragma unroll
    for (int b = 0; b < 2; ++b)
        #pragma unroll
        for (int i = 0; i < 4; ++i)
            lds_t[(rt * 16 + t * 4 + i) * SPITCH + (ct * 2 + b) * 16 + rl] = accd[b][i];
    __syncthreads();

    // readback: thread owns node nd = gid, h-octet ho = hc
    float acc8[8];
    {
        const float4* rp = (const float4*)(lds_t + gid * SPITCH + hc8);
        float4 x = rp[0], y = rp[1];
        acc8[0] = x.x; acc8[1] = x.y; acc8[2] = x.z; acc8[3] = x.w;
        acc8[4] = y.x; acc8[5] = y.y; acc8[6] = y.z; acc8[7] = y.w;
    }

    if (!OUT) {
        ushort* outp = hidden_out + (size_t)node * 64 + hc8;
        unsigned u0 = packbf2(fmaxf(acc8[0], 0.f), fmaxf(acc8[1], 0.f));
        unsigned u1 = packbf2(fmaxf(acc8[2], 0.f), fmaxf(acc8[3], 0.f));
        unsigned u2 = packbf2(fmaxf(acc8[4], 0.f), fmaxf(acc8[5], 0.f));
        unsigned u3 = packbf2(fmaxf(acc8[6], 0.f), fmaxf(acc8[7], 0.f));
        *(uint4*)outp = make_uint4(u0, u1, u2, u3);
    }

    // --- epilogue A: proj for NEXT layer from fp32 acc (exact) ---
    if (PROJ) {
        float pa[AD];
        #pragma unroll
        for (int aa = 0; aa < AD; ++aa) pa[aa] = 0.f;
        #pragma unroll
        for (int i = 0; i < 8; ++i) {
            float hv = fmaxf(acc8[i], 0.f);
            #pragma unroll
            for (int aa = 0; aa < AD; ++aa)
                pa[aa] = fmaf(hv, W1next[aa * 192 + hc8 + i], pa[aa]);
        }
        __syncthreads();
        float* lds2 = lds_t;   // reuse as [256][AD]
        #pragma unroll
        for (int aa = 0; aa < AD; ++aa)
            lds2[tid * AD + aa] = pa[aa];
        __syncthreads();
        int nd = tid >> 3, aa = tid & 7;
        float v = 0.f;
        if (aa < AD) {
            #pragma unroll
            for (int ho = 0; ho < 8; ++ho)
                v += lds2[(nd * 8 + ho) * AD + aa];
        }
        proj_out[(size_t)(node0 + nd) * 8 + aa] = v;
    }

    // --- epilogue B (final layer): fused out = relu(acc).Wc + bc ---
    if (OUT) {
        float po = 0.f;
        #pragma unroll
        for (int i = 0; i < 8; ++i)
            po = fmaf(fmaxf(acc8[i], 0.f), Wc[hc8 + i], po);
        po += __shfl_xor(po, 1);
        po += __shfl_xor(po, 2);
        po += __shfl_xor(po, 4);
        if (hc == 0) outv[node] = po + bc[0];
    }
}

// ---------------------------------------------------------------------------
extern "C" void kernel_launch(void* const* d_in, const int* in_sizes, int n_in,
                              void* d_out, int out_size, void* d_ws, size_t ws_size,
                              hipStream_t stream)
{
    const int*   batch_idx  = (const int*)d_in[0];
    const int*   src_idx    = (const int*)d_in[1];
    const int*   dst_idx    = (const int*)d_in[2];
    const int*   rel_idx    = (const int*)d_in[3];
    const int*   rel_time   = (const int*)d_in[4];
    const int*   query_rel  = (const int*)d_in[5];
    const float* rela_embed = (const float*)d_in[8];   // [3][231][64]
    const float* time_embed = (const float*)d_in[9];   // [365][64]
    const float* Wp         = (const float*)d_in[10];
    const float* Wn         = (const float*)d_in[11];
    const float* Wf         = (const float*)d_in[12];
    const float* W1         = (const float*)d_in[13];  // [3][5][192]
    const float* W2         = (const float*)d_in[14];  // [3][1][5]
    const float* Wc         = (const float*)d_in[15];  // [64]
    const float* bc         = (const float*)d_in[16];  // [1]
    float* out = (float*)d_out;

    char* ws = (char*)d_ws;
    ushort* hid0  = (ushort*)(ws + 0);           // 12.8 MB bf16
    ushort* hid1  = (ushort*)(ws + 12800000);    // 12.8 MB bf16
    float* projA  = (float*)(ws + 25600000);     //  3.2 MB
    float* projB  = (float*)(ws + 28800000);     //  3.2 MB
    float* score  = (float*)(ws + 32000000);     //  4.0 MB
    ushort* WTB   = (ushort*)(ws + 36000000);    //  48 KB bf16 split W frags
    float* Trel   = (float*)(ws + 36100000);     //  ~22 KB
    float* Tq     = (float*)(ws + 36130000);     //  ~22 KB
    int*   off    = (int*)  (ws + 36160000);     // 400 KB (NN+1)
    int2*  meta   = (int2*) (ws + 37400000);     //  8.0 MB
    int*   deg    = (int*)  (ws + 45400000);     // 400 KB
    ushort* relb  = (ushort*)(ws + 45800000);    //  88.7 KB bf16 rela [3][231][64]
    ushort* tembb = (ushort*)(ws + 45950000);    //  46.7 KB bf16 temb [365][64]
    int*   tmp    = (int*)  (ws + 46600000);     // 400 KB
    ushort* rank  = (ushort*)(ws + 47000000);    //  2.0 MB (NE ushorts)
    int*   bsum   = (int*)  (ws + 49000000);     //  ~2 KB
    int*   bpref  = (int*)  (ws + 49010000);     //  ~2 KB

    prep_wtb_kernel<<<12, 256, 0, stream>>>(Wp, Wn, Wf, WTB);
    prep_tb_kernel<<<133, 256, 0, stream>>>(rela_embed, time_embed, relb, tembb);
    prep_tables_kernel<<<NL, 256, 0, stream>>>(rela_embed, W1, Trel, Tq);

    // --- counting sort by dst (rank captured in hist; scatter atomic-free) ---
    hipMemsetAsync(deg, 0, NN * sizeof(int), stream);
    hipMemsetAsync(out, 0, NOUT * sizeof(float), stream);  // zero tail for fused out
    hist_kernel<<<(NE + 255) / 256, 256, 0, stream>>>(dst_idx, deg, rank);
    scan1_kernel<<<NBLK1, 256, 0, stream>>>(deg, tmp, bsum);
    scan2_kernel<<<1, 512, 0, stream>>>(bsum, bpref);
    scan3_kernel<<<NBLK1, 256, 0, stream>>>(deg, tmp, bpref, off);
    sort_scatter_kernel<<<(NE + 255) / 256, 256, 0, stream>>>(
        dst_idx, src_idx, rel_idx, rel_time, batch_idx, query_rel,
        off, rank, Trel, Tq, W2, meta, score);

    // --- layers: L0 -> hid0/projA ; L1 hid0,projA -> hid1/projB ;
    //             L2 hid1,projB -> out (fused Wc dot) ---
    int grid = NBLK2;
    int sgrid = (NE + 255) / 256;
    {
        reduce_transform_kernel<true, true, false><<<grid, 256, 0, stream>>>(
            hid1, relb, tembb, score, meta, off,
            WTB, W1 + (size_t)1 * AD * 192, hid0, projA,
            nullptr, nullptr, nullptr);
    }
    {
        score_kernel<<<sgrid, 256, 0, stream>>>(
            projA, Trel + (size_t)1 * NRL * 8, Tq + (size_t)1 * NRL * 8,
            W2 + 1 * AD, meta, score);
        reduce_transform_kernel<false, true, false><<<grid, 256, 0, stream>>>(
            hid0, relb + (size_t)1 * NRL * HD, tembb, score, meta, off,
            WTB, W1 + (size_t)2 * AD * 192, hid1, projB,
            nullptr, nullptr, nullptr);
    }
    {
        score_kernel<<<sgrid, 256, 0, stream>>>(
            projB, Trel + (size_t)2 * NRL * 8, Tq + (size_t)2 * NRL * 8,
            W2 + 2 * AD, meta, score);
        reduce_transform_kernel<false, false, true><<<grid, 256, 0, stream>>>(
            hid1, relb + (size_t)2 * NRL * HD, tembb, score, meta, off,
            WTB, nullptr, nullptr, nullptr,
            Wc, bc, out);
    }
}

// Round 14
// 424.457 us; speedup vs baseline: 1.0159x; 1.0159x over previous
//
#include <hip/hip_runtime.h>

#define NB   32
#define NN   100000
#define NE   1000000
#define HD   64
#define AD   5
#define NL   3
#define NRL  231      // N_REL + 1
#define NTM  365
#define NOUT 228096   // 32 * 7128
#define NBLK1 391     // ceil(NN/256)
#define BLKN 32       // nodes per reduce block (NN = 3125 * 32 exactly)
#define NBLK2 3125    // NN / BLKN

// meta packing: w0 = src | (rel<<17) | (cls<<25) ; w1 = ta | (q<<9)

// bf16 helpers (hidden stored as bf16 to halve gather traffic)
__device__ __forceinline__ float bflo(unsigned u) { return __uint_as_float(u << 16); }
__device__ __forceinline__ float bfhi(unsigned u) { return __uint_as_float(u & 0xffff0000u); }
__device__ __forceinline__ unsigned packbf2(float x, float y) {
    unsigned ux = __float_as_uint(x), uy = __float_as_uint(y);
    ux = (ux + 0x7fffu + ((ux >> 16) & 1u)) >> 16;
    uy = (uy + 0x7fffu + ((uy >> 16) & 1u)) >> 16;
    return ux | (uy << 16);
}

using vbf8  = __attribute__((ext_vector_type(8))) short;   // 8 bf16 (4 VGPRs) MFMA A/B frag
using f32x4 = __attribute__((ext_vector_type(4))) float;   // MFMA C/D frag

// ---------------------------------------------------------------------------
// WTB: W in bf16 split (hi/lo) laid out as MFMA B-fragments.
// flat idx = ((((c*2 + hl)*2 + ks)*4 + nt)*64 + lane)*8 ushorts
// value(lane, j) = W_c[h = nt*16 + (lane&15)][k = ks*32 + (lane>>4)*8 + j]
// c: 0=Wf(pos) 1=Wn(zero) 2=Wp(neg); hl: 0=hi 1=residual
__global__ __launch_bounds__(256) void prep_wtb_kernel(
    const float* __restrict__ Wp, const float* __restrict__ Wn,
    const float* __restrict__ Wf, ushort* __restrict__ WTB)
{
    int i = blockIdx.x * 256 + threadIdx.x;
    if (i >= 3072) return;
    int lane = i & 63;
    int nt = (i >> 6) & 3;
    int ks = (i >> 8) & 1;
    int hl = (i >> 9) & 1;
    int c  = i >> 10;
    const float* W = (c == 0) ? Wf : (c == 1 ? Wn : Wp);
    int h  = nt * 16 + (lane & 15);
    int k0 = ks * 32 + (lane >> 4) * 8;
    unsigned up[4];
    #pragma unroll
    for (int j = 0; j < 4; ++j) {
        float x = W[h * 64 + k0 + 2 * j];
        float y = W[h * 64 + k0 + 2 * j + 1];
        unsigned pb = packbf2(x, y);
        if (hl) {
            float rx = x - bflo(pb);
            float ry = y - bfhi(pb);
            pb = packbf2(rx, ry);
        }
        up[j] = pb;
    }
    *(uint4*)(WTB + (size_t)i * 8) = make_uint4(up[0], up[1], up[2], up[3]);
}

// ---------------------------------------------------------------------------
// bf16 copies of rela (all 3 layer slices) and temb for the edge-gather phase.
__global__ __launch_bounds__(256) void prep_tb_kernel(
    const float* __restrict__ rela_embed,  // [3][231][64]
    const float* __restrict__ time_embed,  // [365][64]
    ushort* __restrict__ relb,             // [3][231][64] bf16
    ushort* __restrict__ tembb)            // [365][64] bf16
{
    const int nrel_w = 3 * NRL * HD / 2;   // 22176 packed words
    const int ntmb_w = NTM * HD / 2;       // 11680
    int i = blockIdx.x * 256 + threadIdx.x;
    if (i < nrel_w) {
        ((unsigned*)relb)[i] = packbf2(rela_embed[2 * i], rela_embed[2 * i + 1]);
    } else if (i < nrel_w + ntmb_w) {
        int k = i - nrel_w;
        ((unsigned*)tembb)[k] = packbf2(time_embed[2 * k], time_embed[2 * k + 1]);
    }
}

// ---------------------------------------------------------------------------
__global__ __launch_bounds__(256) void prep_tables_kernel(
    const float* __restrict__ rela_embed,   // [3][231][64]
    const float* __restrict__ W1,           // [3][5][192]
    float* __restrict__ Trel,               // [3][231][8]
    float* __restrict__ Tq)                 // [3][231][8]
{
    int l = blockIdx.x;
    int r = threadIdx.x;
    if (r >= NRL) return;
    const float4* rrow = (const float4*)(rela_embed + ((size_t)l * NRL + r) * HD);
    const float* W1l = W1 + (size_t)l * AD * 192;
    float tr[AD] = {0,0,0,0,0}, tq[AD] = {0,0,0,0,0};
    #pragma unroll
    for (int k4 = 0; k4 < 16; ++k4) {
        float4 x = rrow[k4];
        #pragma unroll
        for (int a = 0; a < AD; ++a) {
            const float* wr = W1l + a * 192 + 64 + k4 * 4;
            const float* wq = W1l + a * 192 + 128 + k4 * 4;
            tr[a] = fmaf(x.x, wr[0], tr[a]); tr[a] = fmaf(x.y, wr[1], tr[a]);
            tr[a] = fmaf(x.z, wr[2], tr[a]); tr[a] = fmaf(x.w, wr[3], tr[a]);
            tq[a] = fmaf(x.x, wq[0], tq[a]); tq[a] = fmaf(x.y, wq[1], tq[a]);
            tq[a] = fmaf(x.z, wq[2], tq[a]); tq[a] = fmaf(x.w, wq[3], tq[a]);
        }
    }
    float* tro = Trel + ((size_t)l * NRL + r) * 8;
    float* tqo = Tq   + ((size_t)l * NRL + r) * 8;
    #pragma unroll
    for (int a = 0; a < AD; ++a) { tro[a] = tr[a]; tqo[a] = tq[a]; }
    tro[5] = tro[6] = tro[7] = 0.f;
    tqo[5] = tqo[6] = tqo[7] = 0.f;
}

// ---------------------------------------------------------------------------
// Counting sort by (dst, cls) — R14: class as secondary key makes each node
// segment <=3 uniform-class runs, so the reduce can use ONE running
// accumulator pair (8 FMA/edge) instead of 48 predicated FMAs.
// hist2 captures rank within the (dst,cls) bucket (atomicAdd return,
// fire-and-forget, 300K spread addresses — R3/R9 lessons).
__global__ __launch_bounds__(256) void hist2_kernel(
    const int* __restrict__ dst_idx, const int* __restrict__ rel_time,
    int* __restrict__ deg2, ushort* __restrict__ rank)
{
    int e = blockIdx.x * 256 + threadIdx.x;
    if (e < NE) {
        int d = dst_idx[e];
        int rt = rel_time[e];
        int cls = (rt > 0) ? 0 : ((rt == 0) ? 1 : 2);
        rank[e] = (ushort)atomicAdd(&deg2[d * 3 + cls], 1);
    }
}

__global__ __launch_bounds__(256) void scan1_kernel(
    const int* __restrict__ deg2, int* __restrict__ tmp, int* __restrict__ bsum)
{
    __shared__ int s[256];
    int tid = threadIdx.x;
    int i = blockIdx.x * 256 + tid;
    int v = (i < NN) ? (deg2[3 * i] + deg2[3 * i + 1] + deg2[3 * i + 2]) : 0;
    s[tid] = v;
    __syncthreads();
    #pragma unroll
    for (int st = 1; st < 256; st <<= 1) {
        int t = (tid >= st) ? s[tid - st] : 0;
        __syncthreads();
        s[tid] += t;
        __syncthreads();
    }
    if (i < NN) tmp[i] = s[tid];
    if (tid == 255) bsum[blockIdx.x] = s[255];
}

__global__ __launch_bounds__(512) void scan2_kernel(
    const int* __restrict__ bsum, int* __restrict__ bpref)
{
    __shared__ int s[512];
    int tid = threadIdx.x;
    int v = (tid < NBLK1) ? bsum[tid] : 0;
    s[tid] = v;
    __syncthreads();
    #pragma unroll
    for (int st = 1; st < 512; st <<= 1) {
        int t = (tid >= st) ? s[tid - st] : 0;
        __syncthreads();
        s[tid] += t;
        __syncthreads();
    }
    if (tid < NBLK1) bpref[tid] = s[tid] - v;  // exclusive
}

// off[node] plus per-class bases cbase[3*node+c]
__global__ __launch_bounds__(256) void scan3_kernel(
    const int* __restrict__ deg2, const int* __restrict__ tmp,
    const int* __restrict__ bpref, int* __restrict__ off,
    int* __restrict__ cbase)
{
    int i = blockIdx.x * 256 + threadIdx.x;
    if (i >= NN) return;
    int incl = tmp[i] + bpref[i >> 8];
    int d0 = deg2[3 * i], d1 = deg2[3 * i + 1], d2 = deg2[3 * i + 2];
    int start = incl - (d0 + d1 + d2);
    off[i + 1] = incl;
    cbase[3 * i]     = start;
    cbase[3 * i + 1] = start + d0;
    cbase[3 * i + 2] = start + d0 + d1;
    if (i == 0) off[0] = 0;
}

// scatter into (dst,cls)-sorted order, ATOMIC-FREE: pos = cbase[3d+cls]+rank.
// layer-0 score scatter rides along (random stores fire-and-forget — R3).
__global__ __launch_bounds__(256) void sort_scatter_kernel(
    const int* __restrict__ dst_idx, const int* __restrict__ src_idx,
    const int* __restrict__ rel_idx, const int* __restrict__ rel_time,
    const int* __restrict__ batch_idx, const int* __restrict__ query_rel,
    const int* __restrict__ cbase, const ushort* __restrict__ rank,
    const float* __restrict__ Trel0, const float* __restrict__ Tq0,
    const float* __restrict__ W2,
    int2* __restrict__ meta, float* __restrict__ score0)
{
    int e = blockIdx.x * 256 + threadIdx.x;
    if (e >= NE) return;
    int d = dst_idx[e];
    int rt = rel_time[e];
    int cls = (rt > 0) ? 0 : ((rt == 0) ? 1 : 2);
    int ta = (rt < 0) ? -rt : rt;
    int rel = rel_idx[e];
    int q = query_rel[batch_idx[e]];
    int pos = cbase[d * 3 + cls] + (int)rank[e];
    int2 m;
    m.x = src_idx[e] | (rel << 17) | (cls << 25);
    m.y = ta | (q << 9);
    meta[pos] = m;

    float4 t0 = *(const float4*)(Trel0 + rel * 8);
    float  t4 = Trel0[rel * 8 + 4];
    float4 u0 = *(const float4*)(Tq0 + q * 8);
    float  u4 = Tq0[q * 8 + 4];
    float z = 0.f;
    z = fmaf(fmaxf(t0.x + u0.x, 0.f), W2[0], z);
    z = fmaf(fmaxf(t0.y + u0.y, 0.f), W2[1], z);
    z = fmaf(fmaxf(t0.z + u0.z, 0.f), W2[2], z);
    z = fmaf(fmaxf(t0.w + u0.w, 0.f), W2[3], z);
    z = fmaf(fmaxf(t4   + u4,   0.f), W2[4], z);
    score0[pos] = 1.f / (1.f + __expf(-z));
}

// ---------------------------------------------------------------------------
// Standalone score for L1/L2 (NE-parallel: TLP hides the proj gather — the
// R10 lesson is that this gather must NOT live inside the segment loop).
__global__ __launch_bounds__(256) void score_kernel(
    const float* __restrict__ proj,     // [NN][8]
    const float* __restrict__ Trel,
    const float* __restrict__ Tq,
    const float* __restrict__ W2,
    const int2* __restrict__ meta,
    float* __restrict__ score)
{
    int j = blockIdx.x * 256 + threadIdx.x;
    if (j >= NE) return;
    int2 mt = meta[j];
    int rel = (mt.x >> 17) & 0xFF;
    int q   = (mt.y >> 9) & 0xFF;
    int src = mt.x & 0x1FFFF;

    float4 t0 = *(const float4*)(Trel + rel * 8);
    float  t4 = Trel[rel * 8 + 4];
    float4 u0 = *(const float4*)(Tq + q * 8);
    float  u4 = Tq[q * 8 + 4];
    float4 p0 = *(const float4*)(proj + (size_t)src * 8);
    float  p4 = proj[(size_t)src * 8 + 4];
    float z = 0.f;
    z = fmaf(fmaxf(p0.x + t0.x + u0.x, 0.f), W2[0], z);
    z = fmaf(fmaxf(p0.y + t0.y + u0.y, 0.f), W2[1], z);
    z = fmaf(fmaxf(p0.z + t0.z + u0.z, 0.f), W2[2], z);
    z = fmaf(fmaxf(p0.w + t0.w + u0.w, 0.f), W2[3], z);
    z = fmaf(fmaxf(p4   + t4   + u4,   0.f), W2[4], z);
    score[j] = 1.f / (1.f + __expf(-z));
}

// ---------------------------------------------------------------------------
__device__ __forceinline__ uint4 ldrow(const ushort* __restrict__ base, int row, int hc8)
{
    return *(const uint4*)(base + (size_t)row * HD + hc8);
}

// flush running pair into the statically-indexed class slab (<=3+1 per node)
__device__ __forceinline__ void flushp(int cc, float4 p0, float4 p1, float4* __restrict__ A)
{
    if (cc == 0) {
        A[0].x += p0.x; A[0].y += p0.y; A[0].z += p0.z; A[0].w += p0.w;
        A[1].x += p1.x; A[1].y += p1.y; A[1].z += p1.z; A[1].w += p1.w;
    } else if (cc == 1) {
        A[2].x += p0.x; A[2].y += p0.y; A[2].z += p0.z; A[2].w += p0.w;
        A[3].x += p1.x; A[3].y += p1.y; A[3].z += p1.z; A[3].w += p1.w;
    } else {
        A[4].x += p0.x; A[4].y += p0.y; A[4].z += p0.z; A[4].w += p0.w;
        A[5].x += p1.x; A[5].y += p1.y; A[5].z += p1.z; A[5].w += p1.w;
    }
}

// one edge: class-run boundary check + 8-FMA accumulate into running pair
template <bool HZ>
__device__ __forceinline__ void edge_step(
    int mx, float sc, uint4 rv, uint4 tv, uint4 hv,
    int& cc, float4& p0, float4& p1, float4* __restrict__ A)
{
    int cls = (mx >> 25) & 3;
    if (cls != cc) {
        flushp(cc, p0, p1, A);
        p0 = make_float4(0.f, 0.f, 0.f, 0.f);
        p1 = make_float4(0.f, 0.f, 0.f, 0.f);
        cc = cls;
    }
    float4 v0, v1;
    v0.x = bflo(rv.x) + bflo(tv.x); v0.y = bfhi(rv.x) + bfhi(tv.x);
    v0.z = bflo(rv.y) + bflo(tv.y); v0.w = bfhi(rv.y) + bfhi(tv.y);
    v1.x = bflo(rv.z) + bflo(tv.z); v1.y = bfhi(rv.z) + bfhi(tv.z);
    v1.z = bflo(rv.w) + bflo(tv.w); v1.w = bfhi(rv.w) + bfhi(tv.w);
    if (!HZ) {
        v0.x += bflo(hv.x); v0.y += bfhi(hv.x);
        v0.z += bflo(hv.y); v0.w += bfhi(hv.y);
        v1.x += bflo(hv.z); v1.y += bfhi(hv.z);
        v1.z += bflo(hv.w); v1.w += bfhi(hv.w);
    }
    p0.x = fmaf(sc, v0.x, p0.x); p0.y = fmaf(sc, v0.y, p0.y);
    p0.z = fmaf(sc, v0.z, p0.z); p0.w = fmaf(sc, v0.w, p0.w);
    p1.x = fmaf(sc, v1.x, p1.x); p1.y = fmaf(sc, v1.y, p1.y);
    p1.z = fmaf(sc, v1.z, p1.z); p1.w = fmaf(sc, v1.w, p1.w);
}

// ---------------------------------------------------------------------------
// Fused segmented-reduce + MFMA transform + proj/out epilogue.
// R6: 32-node tile, one node per 8-lane group. R7/R8: bf16 tables + 4-edge
// unroll (R13's deep pipeline REVERTED: 112 VGPR crashed occupancy 33->19%).
// R14: (dst,cls)-sorted edges + running-pair accumulation — 8 FMA/edge
// instead of 48 predicated; class slabs updated only at run boundaries.
#define SPITCH 68
template <bool HZ, bool PROJ, bool OUT>
__global__ __launch_bounds__(256, 4) void reduce_transform_kernel(
    const ushort* __restrict__ hidden_in,   // bf16 [NN][64]
    const ushort* __restrict__ relb,        // layer slice [231][64] bf16
    const ushort* __restrict__ tembb,       // [365][64] bf16
    const float* __restrict__ score,        // [E] sorted
    const int2* __restrict__ meta,          // [E] sorted
    const int*  __restrict__ off,           // [NN+1]
    const ushort* __restrict__ WTB,         // bf16 split W frags [3][2][2][4][64][8]
    const float* __restrict__ W1next,       // next layer slice [5][192] (if PROJ)
    ushort* __restrict__ hidden_out,        // bf16 [NN][64] (if !OUT)
    float* __restrict__ proj_out,           // [NN][8] (if PROJ)
    const float* __restrict__ Wc,           // [64] (if OUT)
    const float* __restrict__ bc,           // [1] (if OUT)
    float* __restrict__ outv)               // [NOUT] (if OUT)
{
    __shared__ float lds_t[BLKN * SPITCH];   // 8704 B
    int tid  = threadIdx.x;
    int lane = tid & 63;
    int w    = __builtin_amdgcn_readfirstlane(tid >> 6);  // 0..3
    int gid  = tid >> 3;                                   // 0..31 (node group)
    int hc   = tid & 7;                                    // 0..7
    int hc8  = hc * 8;
    int node0 = blockIdx.x * BLKN;
    int node  = node0 + gid;                               // NN = 3125*32: always valid

    float4 a[6];
    #pragma unroll
    for (int c = 0; c < 6; ++c)
        a[c] = make_float4(0.f, 0.f, 0.f, 0.f);

    {
        int o0 = off[node];
        int o1 = off[node + 1];
        int j = o0;
        int cc = 0;
        float4 p0 = make_float4(0.f, 0.f, 0.f, 0.f);
        float4 p1 = make_float4(0.f, 0.f, 0.f, 0.f);
        const uint4 zz = make_uint4(0, 0, 0, 0);
        for (; j + 4 <= o1; j += 4) {
            // load phase: 4 edges' rows
            int2 m0 = meta[j],     m1 = meta[j + 1];
            int2 m2 = meta[j + 2], m3 = meta[j + 3];
            float s0 = score[j],     s1 = score[j + 1];
            float s2 = score[j + 2], s3 = score[j + 3];
            uint4 r0 = ldrow(relb, (m0.x >> 17) & 0xFF, hc8);
            uint4 r1 = ldrow(relb, (m1.x >> 17) & 0xFF, hc8);
            uint4 r2 = ldrow(relb, (m2.x >> 17) & 0xFF, hc8);
            uint4 r3 = ldrow(relb, (m3.x >> 17) & 0xFF, hc8);
            uint4 t0 = ldrow(tembb, m0.y & 511, hc8);
            uint4 t1 = ldrow(tembb, m1.y & 511, hc8);
            uint4 t2 = ldrow(tembb, m2.y & 511, hc8);
            uint4 t3 = ldrow(tembb, m3.y & 511, hc8);
            uint4 h0 = zz, h1 = zz, h2 = zz, h3 = zz;
            if (!HZ) {
                h0 = ldrow(hidden_in, m0.x & 0x1FFFF, hc8);
                h1 = ldrow(hidden_in, m1.x & 0x1FFFF, hc8);
                h2 = ldrow(hidden_in, m2.x & 0x1FFFF, hc8);
                h3 = ldrow(hidden_in, m3.x & 0x1FFFF, hc8);
            }
            edge_step<HZ>(m0.x, s0, r0, t0, h0, cc, p0, p1, a);
            edge_step<HZ>(m1.x, s1, r1, t1, h1, cc, p0, p1, a);
            edge_step<HZ>(m2.x, s2, r2, t2, h2, cc, p0, p1, a);
            edge_step<HZ>(m3.x, s3, r3, t3, h3, cc, p0, p1, a);
        }
        for (; j < o1; ++j) {
            int2 m0 = meta[j];
            float s0 = score[j];
            uint4 r0 = ldrow(relb, (m0.x >> 17) & 0xFF, hc8);
            uint4 t0 = ldrow(tembb, m0.y & 511, hc8);
            uint4 h0 = zz;
            if (!HZ) h0 = ldrow(hidden_in, m0.x & 0x1FFFF, hc8);
            edge_step<HZ>(m0.x, s0, r0, t0, h0, cc, p0, p1, a);
        }
        flushp(cc, p0, p1, a);   // final run
    }

    // --- transform via split-bf16 MFMA, one class slab at a time ---
    unsigned* lds_u = (unsigned*)lds_t;
    int rl = lane & 15;
    int t  = lane >> 4;
    int rt = w & 1;    // row-tile (nodes rt*16..rt*16+15)
    int ct = w >> 1;   // col-pair (nt = 2ct, 2ct+1)
    f32x4 accd[2];
    accd[0] = (f32x4){0.f, 0.f, 0.f, 0.f};
    accd[1] = (f32x4){0.f, 0.f, 0.f, 0.f};

    #pragma unroll
    for (int c = 0; c < 3; ++c) {
        __syncthreads();   // protect previous slab's reads
        {
            float4 v0 = a[2 * c];
            float4 v1 = a[2 * c + 1];
            unsigned p0 = packbf2(v0.x, v0.y);
            unsigned p1 = packbf2(v0.z, v0.w);
            unsigned p2 = packbf2(v1.x, v1.y);
            unsigned p3 = packbf2(v1.z, v1.w);
            unsigned q0 = packbf2(v0.x - bflo(p0), v0.y - bfhi(p0));
            unsigned q1 = packbf2(v0.z - bflo(p1), v0.w - bfhi(p1));
            unsigned q2 = packbf2(v1.x - bflo(p2), v1.y - bfhi(p2));
            unsigned q3 = packbf2(v1.z - bflo(p3), v1.w - bfhi(p3));
            *(uint4*)(lds_u + gid * SPITCH + hc * 4)      = make_uint4(p0, p1, p2, p3);
            *(uint4*)(lds_u + gid * SPITCH + 32 + hc * 4) = make_uint4(q0, q1, q2, q3);
        }
        __syncthreads();
        #pragma unroll
        for (int ks = 0; ks < 2; ++ks) {
            const unsigned* rowp = lds_u + (rt * 16 + rl) * SPITCH + ks * 16 + t * 4;
            vbf8 ah = *(const vbf8*)rowp;
            vbf8 al = *(const vbf8*)(rowp + 32);
            #pragma unroll
            for (int b = 0; b < 2; ++b) {
                int nt = ct * 2 + b;
                const ushort* bp = WTB +
                    (size_t)((((c * 2) * 2 + ks) * 4 + nt) * 64 + lane) * 8;
                vbf8 bh = *(const vbf8*)bp;
                vbf8 bl = *(const vbf8*)(bp + 4096);   // hl=1 plane
                accd[b] = __builtin_amdgcn_mfma_f32_16x16x32_bf16(ah, bh, accd[b], 0, 0, 0);
                accd[b] = __builtin_amdgcn_mfma_f32_16x16x32_bf16(al, bh, accd[b], 0, 0, 0);
                accd[b] = __builtin_amdgcn_mfma_f32_16x16x32_bf16(ah, bl, accd[b], 0, 0, 0);
            }
        }
    }

    // D frag (col=lane&15, row=(lane>>4)*4+i) -> LDS [node][h] fp32
    __syncthreads();
    #pragma unroll
    for (int b = 0; b < 2; ++b)
        #pragma unroll
        for (int i = 0; i < 4; ++i)
            lds_t[(rt * 16 + t * 4 + i) * SPITCH + (ct * 2 + b) * 16 + rl] = accd[b][i];
    __syncthreads();

    // readback: thread owns node nd = gid, h-octet ho = hc
    float acc8[8];
    {
        const float4* rp = (const float4*)(lds_t + gid * SPITCH + hc8);
        float4 x = rp[0], y = rp[1];
        acc8[0] = x.x; acc8[1] = x.y; acc8[2] = x.z; acc8[3] = x.w;
        acc8[4] = y.x; acc8[5] = y.y; acc8[6] = y.z; acc8[7] = y.w;
    }

    if (!OUT) {
        ushort* outp = hidden_out + (size_t)node * 64 + hc8;
        unsigned u0 = packbf2(fmaxf(acc8[0], 0.f), fmaxf(acc8[1], 0.f));
        unsigned u1 = packbf2(fmaxf(acc8[2], 0.f), fmaxf(acc8[3], 0.f));
        unsigned u2 = packbf2(fmaxf(acc8[4], 0.f), fmaxf(acc8[5], 0.f));
        unsigned u3 = packbf2(fmaxf(acc8[6], 0.f), fmaxf(acc8[7], 0.f));
        *(uint4*)outp = make_uint4(u0, u1, u2, u3);
    }

    // --- epilogue A: proj for NEXT layer from fp32 acc (exact) ---
    if (PROJ) {
        float pa[AD];
        #pragma unroll
        for (int aa = 0; aa < AD; ++aa) pa[aa] = 0.f;
        #pragma unroll
        for (int i = 0; i < 8; ++i) {
            float hv = fmaxf(acc8[i], 0.f);
            #pragma unroll
            for (int aa = 0; aa < AD; ++aa)
                pa[aa] = fmaf(hv, W1next[aa * 192 + hc8 + i], pa[aa]);
        }
        __syncthreads();
        float* lds2 = lds_t;   // reuse as [256][AD]
        #pragma unroll
        for (int aa = 0; aa < AD; ++aa)
            lds2[tid * AD + aa] = pa[aa];
        __syncthreads();
        int nd = tid >> 3, aa = tid & 7;
        float v = 0.f;
        if (aa < AD) {
            #pragma unroll
            for (int ho = 0; ho < 8; ++ho)
                v += lds2[(nd * 8 + ho) * AD + aa];
        }
        proj_out[(size_t)(node0 + nd) * 8 + aa] = v;
    }

    // --- epilogue B (final layer): fused out = relu(acc).Wc + bc ---
    if (OUT) {
        float po = 0.f;
        #pragma unroll
        for (int i = 0; i < 8; ++i)
            po = fmaf(fmaxf(acc8[i], 0.f), Wc[hc8 + i], po);
        po += __shfl_xor(po, 1);
        po += __shfl_xor(po, 2);
        po += __shfl_xor(po, 4);
        if (hc == 0) outv[node] = po + bc[0];
    }
}

// ---------------------------------------------------------------------------
extern "C" void kernel_launch(void* const* d_in, const int* in_sizes, int n_in,
                              void* d_out, int out_size, void* d_ws, size_t ws_size,
                              hipStream_t stream)
{
    const int*   batch_idx  = (const int*)d_in[0];
    const int*   src_idx    = (const int*)d_in[1];
    const int*   dst_idx    = (const int*)d_in[2];
    const int*   rel_idx    = (const int*)d_in[3];
    const int*   rel_time   = (const int*)d_in[4];
    const int*   query_rel  = (const int*)d_in[5];
    const float* rela_embed = (const float*)d_in[8];   // [3][231][64]
    const float* time_embed = (const float*)d_in[9];   // [365][64]
    const float* Wp         = (const float*)d_in[10];
    const float* Wn         = (const float*)d_in[11];
    const float* Wf         = (const float*)d_in[12];
    const float* W1         = (const float*)d_in[13];  // [3][5][192]
    const float* W2         = (const float*)d_in[14];  // [3][1][5]
    const float* Wc         = (const float*)d_in[15];  // [64]
    const float* bc         = (const float*)d_in[16];  // [1]
    float* out = (float*)d_out;

    char* ws = (char*)d_ws;
    ushort* hid0  = (ushort*)(ws + 0);           // 12.8 MB bf16
    ushort* hid1  = (ushort*)(ws + 12800000);    // 12.8 MB bf16
    // sort-phase scratch ALIASES projA/projB (dead until L0 reduce runs):
    int*   deg2   = (int*)  (ws + 25600000);     //  1.2 MB (3*NN)
    int*   cbase  = (int*)  (ws + 26800000);     //  1.2 MB (3*NN)
    int*   tmp    = (int*)  (ws + 28000000);     //  0.4 MB
    ushort* rank  = (ushort*)(ws + 28400000);    //  2.0 MB (NE ushorts)
    float* projA  = (float*)(ws + 25600000);     //  3.2 MB (live from L0 reduce)
    float* projB  = (float*)(ws + 28800000);     //  3.2 MB -- NOTE: rank overlaps
    float* score  = (float*)(ws + 32000000);     //  4.0 MB
    ushort* WTB   = (ushort*)(ws + 36000000);    //  48 KB bf16 split W frags
    float* Trel   = (float*)(ws + 36100000);     //  ~22 KB
    float* Tq     = (float*)(ws + 36130000);     //  ~22 KB
    int*   off    = (int*)  (ws + 36160000);     // 400 KB (NN+1)
    ushort* relb  = (ushort*)(ws + 36600000);    //  88.7 KB bf16 rela
    ushort* tembb = (ushort*)(ws + 36700000);    //  46.7 KB bf16 temb
    int2*  meta   = (int2*) (ws + 37400000);     //  8.0 MB
    int*   bsum   = (int*)  (ws + 49000000);     //  ~2 KB
    int*   bpref  = (int*)  (ws + 49010000);     //  ~2 KB
    // projB (28800000..32000000) overlaps rank (28400000..30400000): rank is
    // dead after sort_scatter; projB first written by L0 reduce (later). Safe.

    prep_wtb_kernel<<<12, 256, 0, stream>>>(Wp, Wn, Wf, WTB);
    prep_tb_kernel<<<133, 256, 0, stream>>>(rela_embed, time_embed, relb, tembb);
    prep_tables_kernel<<<NL, 256, 0, stream>>>(rela_embed, W1, Trel, Tq);

    // --- counting sort by (dst, cls); scatter atomic-free ---
    hipMemsetAsync(deg2, 0, 3 * NN * sizeof(int), stream);
    hipMemsetAsync(out, 0, NOUT * sizeof(float), stream);  // zero tail for fused out
    hist2_kernel<<<(NE + 255) / 256, 256, 0, stream>>>(dst_idx, rel_time, deg2, rank);
    scan1_kernel<<<NBLK1, 256, 0, stream>>>(deg2, tmp, bsum);
    scan2_kernel<<<1, 512, 0, stream>>>(bsum, bpref);
    scan3_kernel<<<NBLK1, 256, 0, stream>>>(deg2, tmp, bpref, off, cbase);
    sort_scatter_kernel<<<(NE + 255) / 256, 256, 0, stream>>>(
        dst_idx, src_idx, rel_idx, rel_time, batch_idx, query_rel,
        cbase, rank, Trel, Tq, W2, meta, score);

    // --- layers: L0 -> hid0/projA ; L1 hid0,projA -> hid1/projB ;
    //             L2 hid1,projB -> out (fused Wc dot) ---
    int grid = NBLK2;
    int sgrid = (NE + 255) / 256;
    {
        reduce_transform_kernel<true, true, false><<<grid, 256, 0, stream>>>(
            hid1, relb, tembb, score, meta, off,
            WTB, W1 + (size_t)1 * AD * 192, hid0, projA,
            nullptr, nullptr, nullptr);
    }
    {
        score_kernel<<<sgrid, 256, 0, stream>>>(
            projA, Trel + (size_t)1 * NRL * 8, Tq + (size_t)1 * NRL * 8,
            W2 + 1 * AD, meta, score);
        reduce_transform_kernel<false, true, false><<<grid, 256, 0, stream>>>(
            hid0, relb + (size_t)1 * NRL * HD, tembb, score, meta, off,
            WTB, W1 + (size_t)2 * AD * 192, hid1, projB,
            nullptr, nullptr, nullptr);
    }
    {
        score_kernel<<<sgrid, 256, 0, stream>>>(
            projB, Trel + (size_t)2 * NRL * 8, Tq + (size_t)2 * NRL * 8,
            W2 + 2 * AD, meta, score);
        reduce_transform_kernel<false, false, true><<<grid, 256, 0, stream>>>(
            hid1, relb + (size_t)2 * NRL * HD, tembb, score, meta, off,
            WTB, nullptr, nullptr, nullptr,
            Wc, bc, out);
    }
}

// Round 15
// 381.482 us; speedup vs baseline: 1.1303x; 1.1127x over previous
//
#include <hip/hip_runtime.h>

#define NB   32
#define NN   100000
#define NE   1000000
#define HD   64
#define AD   5
#define NL   3
#define NRL  231      // N_REL + 1
#define NTM  365
#define NOUT 228096   // 32 * 7128
#define NBLK1 391     // ceil(NN/256)
#define BLKN 32       // nodes per reduce block (NN = 3125 * 32 exactly)
#define NBLK2 3125    // NN / BLKN

// meta packing: w0 = src | (rel<<17) | (cls<<25) ; w1 = ta | (q<<9)

// bf16 helpers (hidden stored as bf16 to halve gather traffic)
__device__ __forceinline__ float bflo(unsigned u) { return __uint_as_float(u << 16); }
__device__ __forceinline__ float bfhi(unsigned u) { return __uint_as_float(u & 0xffff0000u); }
__device__ __forceinline__ unsigned packbf2(float x, float y) {
    unsigned ux = __float_as_uint(x), uy = __float_as_uint(y);
    ux = (ux + 0x7fffu + ((ux >> 16) & 1u)) >> 16;
    uy = (uy + 0x7fffu + ((uy >> 16) & 1u)) >> 16;
    return ux | (uy << 16);
}

using vbf8  = __attribute__((ext_vector_type(8))) short;   // 8 bf16 (4 VGPRs) MFMA A/B frag
using f32x4 = __attribute__((ext_vector_type(4))) float;   // MFMA C/D frag

// ---------------------------------------------------------------------------
// WTB: W in bf16 split (hi/lo) laid out as MFMA B-fragments.
// flat idx = ((((c*2 + hl)*2 + ks)*4 + nt)*64 + lane)*8 ushorts
// value(lane, j) = W_c[h = nt*16 + (lane&15)][k = ks*32 + (lane>>4)*8 + j]
// c: 0=Wf(pos) 1=Wn(zero) 2=Wp(neg); hl: 0=hi 1=residual
__global__ __launch_bounds__(256) void prep_wtb_kernel(
    const float* __restrict__ Wp, const float* __restrict__ Wn,
    const float* __restrict__ Wf, ushort* __restrict__ WTB)
{
    int i = blockIdx.x * 256 + threadIdx.x;
    if (i >= 3072) return;
    int lane = i & 63;
    int nt = (i >> 6) & 3;
    int ks = (i >> 8) & 1;
    int hl = (i >> 9) & 1;
    int c  = i >> 10;
    const float* W = (c == 0) ? Wf : (c == 1 ? Wn : Wp);
    int h  = nt * 16 + (lane & 15);
    int k0 = ks * 32 + (lane >> 4) * 8;
    unsigned up[4];
    #pragma unroll
    for (int j = 0; j < 4; ++j) {
        float x = W[h * 64 + k0 + 2 * j];
        float y = W[h * 64 + k0 + 2 * j + 1];
        unsigned pb = packbf2(x, y);
        if (hl) {
            float rx = x - bflo(pb);
            float ry = y - bfhi(pb);
            pb = packbf2(rx, ry);
        }
        up[j] = pb;
    }
    *(uint4*)(WTB + (size_t)i * 8) = make_uint4(up[0], up[1], up[2], up[3]);
}

// ---------------------------------------------------------------------------
// bf16 copies of rela (all 3 layer slices) and temb for the edge-gather phase.
__global__ __launch_bounds__(256) void prep_tb_kernel(
    const float* __restrict__ rela_embed,  // [3][231][64]
    const float* __restrict__ time_embed,  // [365][64]
    ushort* __restrict__ relb,             // [3][231][64] bf16
    ushort* __restrict__ tembb)            // [365][64] bf16
{
    const int nrel_w = 3 * NRL * HD / 2;   // 22176 packed words
    const int ntmb_w = NTM * HD / 2;       // 11680
    int i = blockIdx.x * 256 + threadIdx.x;
    if (i < nrel_w) {
        ((unsigned*)relb)[i] = packbf2(rela_embed[2 * i], rela_embed[2 * i + 1]);
    } else if (i < nrel_w + ntmb_w) {
        int k = i - nrel_w;
        ((unsigned*)tembb)[k] = packbf2(time_embed[2 * k], time_embed[2 * k + 1]);
    }
}

// ---------------------------------------------------------------------------
__global__ __launch_bounds__(256) void prep_tables_kernel(
    const float* __restrict__ rela_embed,   // [3][231][64]
    const float* __restrict__ W1,           // [3][5][192]
    float* __restrict__ Trel,               // [3][231][8]
    float* __restrict__ Tq)                 // [3][231][8]
{
    int l = blockIdx.x;
    int r = threadIdx.x;
    if (r >= NRL) return;
    const float4* rrow = (const float4*)(rela_embed + ((size_t)l * NRL + r) * HD);
    const float* W1l = W1 + (size_t)l * AD * 192;
    float tr[AD] = {0,0,0,0,0}, tq[AD] = {0,0,0,0,0};
    #pragma unroll
    for (int k4 = 0; k4 < 16; ++k4) {
        float4 x = rrow[k4];
        #pragma unroll
        for (int a = 0; a < AD; ++a) {
            const float* wr = W1l + a * 192 + 64 + k4 * 4;
            const float* wq = W1l + a * 192 + 128 + k4 * 4;
            tr[a] = fmaf(x.x, wr[0], tr[a]); tr[a] = fmaf(x.y, wr[1], tr[a]);
            tr[a] = fmaf(x.z, wr[2], tr[a]); tr[a] = fmaf(x.w, wr[3], tr[a]);
            tq[a] = fmaf(x.x, wq[0], tq[a]); tq[a] = fmaf(x.y, wq[1], tq[a]);
            tq[a] = fmaf(x.z, wq[2], tq[a]); tq[a] = fmaf(x.w, wq[3], tq[a]);
        }
    }
    float* tro = Trel + ((size_t)l * NRL + r) * 8;
    float* tqo = Tq   + ((size_t)l * NRL + r) * 8;
    #pragma unroll
    for (int a = 0; a < AD; ++a) { tro[a] = tr[a]; tqo[a] = tq[a]; }
    tro[5] = tro[6] = tro[7] = 0.f;
    tqo[5] = tqo[6] = tqo[7] = 0.f;
}

// ---------------------------------------------------------------------------
// Counting sort by dst. hist captures each edge's rank within its dst bucket
// (atomicAdd return, fire-and-forget); the scatter then needs NO atomic (R5).
__global__ __launch_bounds__(256) void hist_kernel(
    const int* __restrict__ dst_idx, int* __restrict__ deg,
    ushort* __restrict__ rank)
{
    int e = blockIdx.x * 256 + threadIdx.x;
    if (e < NE) rank[e] = (ushort)atomicAdd(&deg[dst_idx[e]], 1);
}

__global__ __launch_bounds__(256) void scan1_kernel(
    const int* __restrict__ deg, int* __restrict__ tmp, int* __restrict__ bsum)
{
    __shared__ int s[256];
    int tid = threadIdx.x;
    int i = blockIdx.x * 256 + tid;
    int v = (i < NN) ? deg[i] : 0;
    s[tid] = v;
    __syncthreads();
    #pragma unroll
    for (int st = 1; st < 256; st <<= 1) {
        int t = (tid >= st) ? s[tid - st] : 0;
        __syncthreads();
        s[tid] += t;
        __syncthreads();
    }
    if (i < NN) tmp[i] = s[tid];
    if (tid == 255) bsum[blockIdx.x] = s[255];
}

__global__ __launch_bounds__(512) void scan2_kernel(
    const int* __restrict__ bsum, int* __restrict__ bpref)
{
    __shared__ int s[512];
    int tid = threadIdx.x;
    int v = (tid < NBLK1) ? bsum[tid] : 0;
    s[tid] = v;
    __syncthreads();
    #pragma unroll
    for (int st = 1; st < 512; st <<= 1) {
        int t = (tid >= st) ? s[tid - st] : 0;
        __syncthreads();
        s[tid] += t;
        __syncthreads();
    }
    if (tid < NBLK1) bpref[tid] = s[tid] - v;  // exclusive
}

__global__ __launch_bounds__(256) void scan3_kernel(
    const int* __restrict__ deg, const int* __restrict__ tmp,
    const int* __restrict__ bpref, int* __restrict__ off)
{
    int i = blockIdx.x * 256 + threadIdx.x;
    if (i >= NN) return;
    int incl = tmp[i] + bpref[i >> 8];
    off[i + 1] = incl;
    if (i == 0) off[0] = 0;
}

// scatter into dst-sorted order, ATOMIC-FREE: pos = off[d] + rank[e].
// R8 form: layer-0 score scatter rides along (random stores are
// fire-and-forget — R3 lesson).
__global__ __launch_bounds__(256) void sort_scatter_kernel(
    const int* __restrict__ dst_idx, const int* __restrict__ src_idx,
    const int* __restrict__ rel_idx, const int* __restrict__ rel_time,
    const int* __restrict__ batch_idx, const int* __restrict__ query_rel,
    const int* __restrict__ off, const ushort* __restrict__ rank,
    const float* __restrict__ Trel0, const float* __restrict__ Tq0,
    const float* __restrict__ W2,
    int2* __restrict__ meta, float* __restrict__ score0)
{
    int e = blockIdx.x * 256 + threadIdx.x;
    if (e >= NE) return;
    int d = dst_idx[e];
    int rt = rel_time[e];
    int cls = (rt > 0) ? 0 : ((rt == 0) ? 1 : 2);
    int ta = (rt < 0) ? -rt : rt;
    int rel = rel_idx[e];
    int q = query_rel[batch_idx[e]];
    int pos = off[d] + (int)rank[e];
    int2 m;
    m.x = src_idx[e] | (rel << 17) | (cls << 25);
    m.y = ta | (q << 9);
    meta[pos] = m;

    float4 t0 = *(const float4*)(Trel0 + rel * 8);
    float  t4 = Trel0[rel * 8 + 4];
    float4 u0 = *(const float4*)(Tq0 + q * 8);
    float  u4 = Tq0[q * 8 + 4];
    float z = 0.f;
    z = fmaf(fmaxf(t0.x + u0.x, 0.f), W2[0], z);
    z = fmaf(fmaxf(t0.y + u0.y, 0.f), W2[1], z);
    z = fmaf(fmaxf(t0.z + u0.z, 0.f), W2[2], z);
    z = fmaf(fmaxf(t0.w + u0.w, 0.f), W2[3], z);
    z = fmaf(fmaxf(t4   + u4,   0.f), W2[4], z);
    score0[pos] = 1.f / (1.f + __expf(-z));
}

// ---------------------------------------------------------------------------
// Standalone score for L1/L2 (NE-parallel: TLP hides the proj gather — the
// R10 lesson is that this gather must NOT live inside the segment loop).
__global__ __launch_bounds__(256) void score_kernel(
    const float* __restrict__ proj,     // [NN][8]
    const float* __restrict__ Trel,
    const float* __restrict__ Tq,
    const float* __restrict__ W2,
    const int2* __restrict__ meta,
    float* __restrict__ score)
{
    int j = blockIdx.x * 256 + threadIdx.x;
    if (j >= NE) return;
    int2 mt = meta[j];
    int rel = (mt.x >> 17) & 0xFF;
    int q   = (mt.y >> 9) & 0xFF;
    int src = mt.x & 0x1FFFF;

    float4 t0 = *(const float4*)(Trel + rel * 8);
    float  t4 = Trel[rel * 8 + 4];
    float4 u0 = *(const float4*)(Tq + q * 8);
    float  u4 = Tq[q * 8 + 4];
    float4 p0 = *(const float4*)(proj + (size_t)src * 8);
    float  p4 = proj[(size_t)src * 8 + 4];
    float z = 0.f;
    z = fmaf(fmaxf(p0.x + t0.x + u0.x, 0.f), W2[0], z);
    z = fmaf(fmaxf(p0.y + t0.y + u0.y, 0.f), W2[1], z);
    z = fmaf(fmaxf(p0.z + t0.z + u0.z, 0.f), W2[2], z);
    z = fmaf(fmaxf(p0.w + t0.w + u0.w, 0.f), W2[3], z);
    z = fmaf(fmaxf(p4   + t4   + u4,   0.f), W2[4], z);
    score[j] = 1.f / (1.f + __expf(-z));
}

// ---------------------------------------------------------------------------
// Accumulate one edge from preloaded bf16 rows (rv=rela, tv=temb, hv=hidden).
// A[6] = [cls0 h0..3, cls0 h4..7, cls1 lo, cls1 hi, cls2 lo, cls2 hi]
template <bool HZ>
__device__ __forceinline__ void edge_acc(
    int mx, float sc, uint4 rv, uint4 tv, uint4 hv, float4* __restrict__ A)
{
    int cl = (mx >> 25) & 3;
    float4 v0, v1;
    v0.x = bflo(rv.x) + bflo(tv.x); v0.y = bfhi(rv.x) + bfhi(tv.x);
    v0.z = bflo(rv.y) + bflo(tv.y); v0.w = bfhi(rv.y) + bfhi(tv.y);
    v1.x = bflo(rv.z) + bflo(tv.z); v1.y = bfhi(rv.z) + bfhi(tv.z);
    v1.z = bflo(rv.w) + bflo(tv.w); v1.w = bfhi(rv.w) + bfhi(tv.w);
    if (!HZ) {
        v0.x += bflo(hv.x); v0.y += bfhi(hv.x);
        v0.z += bflo(hv.y); v0.w += bfhi(hv.y);
        v1.x += bflo(hv.z); v1.y += bfhi(hv.z);
        v1.z += bflo(hv.w); v1.w += bfhi(hv.w);
    }
    float sA = (cl == 0) ? sc : 0.f;
    float sB = (cl == 1) ? sc : 0.f;
    float sC = (cl == 2) ? sc : 0.f;
    A[0].x = fmaf(sA, v0.x, A[0].x); A[0].y = fmaf(sA, v0.y, A[0].y);
    A[0].z = fmaf(sA, v0.z, A[0].z); A[0].w = fmaf(sA, v0.w, A[0].w);
    A[1].x = fmaf(sA, v1.x, A[1].x); A[1].y = fmaf(sA, v1.y, A[1].y);
    A[1].z = fmaf(sA, v1.z, A[1].z); A[1].w = fmaf(sA, v1.w, A[1].w);
    A[2].x = fmaf(sB, v0.x, A[2].x); A[2].y = fmaf(sB, v0.y, A[2].y);
    A[2].z = fmaf(sB, v0.z, A[2].z); A[2].w = fmaf(sB, v0.w, A[2].w);
    A[3].x = fmaf(sB, v1.x, A[3].x); A[3].y = fmaf(sB, v1.y, A[3].y);
    A[3].z = fmaf(sB, v1.z, A[3].z); A[3].w = fmaf(sB, v1.w, A[3].w);
    A[4].x = fmaf(sC, v0.x, A[4].x); A[4].y = fmaf(sC, v0.y, A[4].y);
    A[4].z = fmaf(sC, v0.z, A[4].z); A[4].w = fmaf(sC, v0.w, A[4].w);
    A[5].x = fmaf(sC, v1.x, A[5].x); A[5].y = fmaf(sC, v1.y, A[5].y);
    A[5].z = fmaf(sC, v1.z, A[5].z); A[5].w = fmaf(sC, v1.w, A[5].w);
}

__device__ __forceinline__ uint4 ldrow(const ushort* __restrict__ base, int row, int hc8)
{
    return *(const uint4*)(base + (size_t)row * HD + hc8);
}

// ---------------------------------------------------------------------------
// Fused segmented-reduce + MFMA transform + proj/out epilogue.
// Best measured configuration (R12, 381.7 us): 32-node tile, one node per
// 8-lane group, bf16 tables, 4-edge unroll, fused final Wc-dot.
// Edge-loop optimization ledger (all measured, all reverted):
//   R6 more TLP -8%; R8 bf16 tables+ILP -4%; R9 degree-balance 0%;
//   R10 score fusion -25%; R12 reg budget 0%; R13 SW pipeline -25%
//   (112 VGPR, occupancy 33->19%); R14 class-sort+running-pair -18%
//   (compiler demoted accumulators to scratch: WRITE_SIZE 15.6->133 MB).
// The loop is latency-bound on distributed small gathers; no saturated pipe.
#define SPITCH 68
template <bool HZ, bool PROJ, bool OUT>
__global__ __launch_bounds__(256, 2) void reduce_transform_kernel(
    const ushort* __restrict__ hidden_in,   // bf16 [NN][64]
    const ushort* __restrict__ relb,        // layer slice [231][64] bf16
    const ushort* __restrict__ tembb,       // [365][64] bf16
    const float* __restrict__ score,        // [E] sorted
    const int2* __restrict__ meta,          // [E] sorted
    const int*  __restrict__ off,           // [NN+1]
    const ushort* __restrict__ WTB,         // bf16 split W frags [3][2][2][4][64][8]
    const float* __restrict__ W1next,       // next layer slice [5][192] (if PROJ)
    ushort* __restrict__ hidden_out,        // bf16 [NN][64] (if !OUT)
    float* __restrict__ proj_out,           // [NN][8] (if PROJ)
    const float* __restrict__ Wc,           // [64] (if OUT)
    const float* __restrict__ bc,           // [1] (if OUT)
    float* __restrict__ outv)               // [NOUT] (if OUT)
{
    __shared__ float lds_t[BLKN * SPITCH];   // 8704 B
    int tid  = threadIdx.x;
    int lane = tid & 63;
    int w    = __builtin_amdgcn_readfirstlane(tid >> 6);  // 0..3
    int gid  = tid >> 3;                                   // 0..31 (node group)
    int hc   = tid & 7;                                    // 0..7
    int hc8  = hc * 8;
    int node0 = blockIdx.x * BLKN;
    int node  = node0 + gid;                               // NN = 3125*32: always valid

    float4 a[6];
    #pragma unroll
    for (int c = 0; c < 6; ++c)
        a[c] = make_float4(0.f, 0.f, 0.f, 0.f);

    {
        int o0 = off[node];
        int o1 = off[node + 1];
        int j = o0;
        const uint4 zz = make_uint4(0, 0, 0, 0);
        for (; j + 4 <= o1; j += 4) {
            // load phase: 4 independent chains
            int2 m0 = meta[j],     m1 = meta[j + 1];
            int2 m2 = meta[j + 2], m3 = meta[j + 3];
            float s0 = score[j],     s1 = score[j + 1];
            float s2 = score[j + 2], s3 = score[j + 3];
            uint4 r0 = ldrow(relb, (m0.x >> 17) & 0xFF, hc8);
            uint4 r1 = ldrow(relb, (m1.x >> 17) & 0xFF, hc8);
            uint4 r2 = ldrow(relb, (m2.x >> 17) & 0xFF, hc8);
            uint4 r3 = ldrow(relb, (m3.x >> 17) & 0xFF, hc8);
            uint4 t0 = ldrow(tembb, m0.y & 511, hc8);
            uint4 t1 = ldrow(tembb, m1.y & 511, hc8);
            uint4 t2 = ldrow(tembb, m2.y & 511, hc8);
            uint4 t3 = ldrow(tembb, m3.y & 511, hc8);
            uint4 h0 = zz, h1 = zz, h2 = zz, h3 = zz;
            if (!HZ) {
                h0 = ldrow(hidden_in, m0.x & 0x1FFFF, hc8);
                h1 = ldrow(hidden_in, m1.x & 0x1FFFF, hc8);
                h2 = ldrow(hidden_in, m2.x & 0x1FFFF, hc8);
                h3 = ldrow(hidden_in, m3.x & 0x1FFFF, hc8);
            }
            edge_acc<HZ>(m0.x, s0, r0, t0, h0, a);
            edge_acc<HZ>(m1.x, s1, r1, t1, h1, a);
            edge_acc<HZ>(m2.x, s2, r2, t2, h2, a);
            edge_acc<HZ>(m3.x, s3, r3, t3, h3, a);
        }
        for (; j < o1; ++j) {
            int2 m0 = meta[j];
            float s0 = score[j];
            uint4 r0 = ldrow(relb, (m0.x >> 17) & 0xFF, hc8);
            uint4 t0 = ldrow(tembb, m0.y & 511, hc8);
            uint4 h0 = zz;
            if (!HZ) h0 = ldrow(hidden_in, m0.x & 0x1FFFF, hc8);
            edge_acc<HZ>(m0.x, s0, r0, t0, h0, a);
        }
    }

    // --- transform via split-bf16 MFMA, one class slab at a time ---
    unsigned* lds_u = (unsigned*)lds_t;
    int rl = lane & 15;
    int t  = lane >> 4;
    int rt = w & 1;    // row-tile (nodes rt*16..rt*16+15)
    int ct = w >> 1;   // col-pair (nt = 2ct, 2ct+1)
    f32x4 accd[2];
    accd[0] = (f32x4){0.f, 0.f, 0.f, 0.f};
    accd[1] = (f32x4){0.f, 0.f, 0.f, 0.f};

    #pragma unroll
    for (int c = 0; c < 3; ++c) {
        __syncthreads();   // protect previous slab's reads
        {
            float4 v0 = a[2 * c];
            float4 v1 = a[2 * c + 1];
            unsigned p0 = packbf2(v0.x, v0.y);
            unsigned p1 = packbf2(v0.z, v0.w);
            unsigned p2 = packbf2(v1.x, v1.y);
            unsigned p3 = packbf2(v1.z, v1.w);
            unsigned q0 = packbf2(v0.x - bflo(p0), v0.y - bfhi(p0));
            unsigned q1 = packbf2(v0.z - bflo(p1), v0.w - bfhi(p1));
            unsigned q2 = packbf2(v1.x - bflo(p2), v1.y - bfhi(p2));
            unsigned q3 = packbf2(v1.z - bflo(p3), v1.w - bfhi(p3));
            *(uint4*)(lds_u + gid * SPITCH + hc * 4)      = make_uint4(p0, p1, p2, p3);
            *(uint4*)(lds_u + gid * SPITCH + 32 + hc * 4) = make_uint4(q0, q1, q2, q3);
        }
        __syncthreads();
        #pragma unroll
        for (int ks = 0; ks < 2; ++ks) {
            const unsigned* rowp = lds_u + (rt * 16 + rl) * SPITCH + ks * 16 + t * 4;
            vbf8 ah = *(const vbf8*)rowp;
            vbf8 al = *(const vbf8*)(rowp + 32);
            #pragma unroll
            for (int b = 0; b < 2; ++b) {
                int nt = ct * 2 + b;
                const ushort* bp = WTB +
                    (size_t)((((c * 2) * 2 + ks) * 4 + nt) * 64 + lane) * 8;
                vbf8 bh = *(const vbf8*)bp;
                vbf8 bl = *(const vbf8*)(bp + 4096);   // hl=1 plane
                accd[b] = __builtin_amdgcn_mfma_f32_16x16x32_bf16(ah, bh, accd[b], 0, 0, 0);
                accd[b] = __builtin_amdgcn_mfma_f32_16x16x32_bf16(al, bh, accd[b], 0, 0, 0);
                accd[b] = __builtin_amdgcn_mfma_f32_16x16x32_bf16(ah, bl, accd[b], 0, 0, 0);
            }
        }
    }

    // D frag (col=lane&15, row=(lane>>4)*4+i) -> LDS [node][h] fp32
    __syncthreads();
    #pragma unroll
    for (int b = 0; b < 2; ++b)
        #pragma unroll
        for (int i = 0; i < 4; ++i)
            lds_t[(rt * 16 + t * 4 + i) * SPITCH + (ct * 2 + b) * 16 + rl] = accd[b][i];
    __syncthreads();

    // readback: thread owns node nd = gid, h-octet ho = hc
    float acc8[8];
    {
        const float4* rp = (const float4*)(lds_t + gid * SPITCH + hc8);
        float4 x = rp[0], y = rp[1];
        acc8[0] = x.x; acc8[1] = x.y; acc8[2] = x.z; acc8[3] = x.w;
        acc8[4] = y.x; acc8[5] = y.y; acc8[6] = y.z; acc8[7] = y.w;
    }

    if (!OUT) {
        ushort* outp = hidden_out + (size_t)node * 64 + hc8;
        unsigned u0 = packbf2(fmaxf(acc8[0], 0.f), fmaxf(acc8[1], 0.f));
        unsigned u1 = packbf2(fmaxf(acc8[2], 0.f), fmaxf(acc8[3], 0.f));
        unsigned u2 = packbf2(fmaxf(acc8[4], 0.f), fmaxf(acc8[5], 0.f));
        unsigned u3 = packbf2(fmaxf(acc8[6], 0.f), fmaxf(acc8[7], 0.f));
        *(uint4*)outp = make_uint4(u0, u1, u2, u3);
    }

    // --- epilogue A: proj for NEXT layer from fp32 acc (exact) ---
    if (PROJ) {
        float pa[AD];
        #pragma unroll
        for (int aa = 0; aa < AD; ++aa) pa[aa] = 0.f;
        #pragma unroll
        for (int i = 0; i < 8; ++i) {
            float hv = fmaxf(acc8[i], 0.f);
            #pragma unroll
            for (int aa = 0; aa < AD; ++aa)
                pa[aa] = fmaf(hv, W1next[aa * 192 + hc8 + i], pa[aa]);
        }
        __syncthreads();
        float* lds2 = lds_t;   // reuse as [256][AD]
        #pragma unroll
        for (int aa = 0; aa < AD; ++aa)
            lds2[tid * AD + aa] = pa[aa];
        __syncthreads();
        int nd = tid >> 3, aa = tid & 7;
        float v = 0.f;
        if (aa < AD) {
            #pragma unroll
            for (int ho = 0; ho < 8; ++ho)
                v += lds2[(nd * 8 + ho) * AD + aa];
        }
        proj_out[(size_t)(node0 + nd) * 8 + aa] = v;
    }

    // --- epilogue B (final layer): fused out = relu(acc).Wc + bc ---
    if (OUT) {
        float po = 0.f;
        #pragma unroll
        for (int i = 0; i < 8; ++i)
            po = fmaf(fmaxf(acc8[i], 0.f), Wc[hc8 + i], po);
        po += __shfl_xor(po, 1);
        po += __shfl_xor(po, 2);
        po += __shfl_xor(po, 4);
        if (hc == 0) outv[node] = po + bc[0];
    }
}

// ---------------------------------------------------------------------------
extern "C" void kernel_launch(void* const* d_in, const int* in_sizes, int n_in,
                              void* d_out, int out_size, void* d_ws, size_t ws_size,
                              hipStream_t stream)
{
    const int*   batch_idx  = (const int*)d_in[0];
    const int*   src_idx    = (const int*)d_in[1];
    const int*   dst_idx    = (const int*)d_in[2];
    const int*   rel_idx    = (const int*)d_in[3];
    const int*   rel_time   = (const int*)d_in[4];
    const int*   query_rel  = (const int*)d_in[5];
    const float* rela_embed = (const float*)d_in[8];   // [3][231][64]
    const float* time_embed = (const float*)d_in[9];   // [365][64]
    const float* Wp         = (const float*)d_in[10];
    const float* Wn         = (const float*)d_in[11];
    const float* Wf         = (const float*)d_in[12];
    const float* W1         = (const float*)d_in[13];  // [3][5][192]
    const float* W2         = (const float*)d_in[14];  // [3][1][5]
    const float* Wc         = (const float*)d_in[15];  // [64]
    const float* bc         = (const float*)d_in[16];  // [1]
    float* out = (float*)d_out;

    char* ws = (char*)d_ws;
    ushort* hid0  = (ushort*)(ws + 0);           // 12.8 MB bf16
    ushort* hid1  = (ushort*)(ws + 12800000);    // 12.8 MB bf16
    float* projA  = (float*)(ws + 25600000);     //  3.2 MB
    float* projB  = (float*)(ws + 28800000);     //  3.2 MB
    float* score  = (float*)(ws + 32000000);     //  4.0 MB
    ushort* WTB   = (ushort*)(ws + 36000000);    //  48 KB bf16 split W frags
    float* Trel   = (float*)(ws + 36100000);     //  ~22 KB
    float* Tq     = (float*)(ws + 36130000);     //  ~22 KB
    int*   off    = (int*)  (ws + 36160000);     // 400 KB (NN+1)
    int2*  meta   = (int2*) (ws + 37400000);     //  8.0 MB
    int*   deg    = (int*)  (ws + 45400000);     // 400 KB
    ushort* relb  = (ushort*)(ws + 45800000);    //  88.7 KB bf16 rela [3][231][64]
    ushort* tembb = (ushort*)(ws + 45950000);    //  46.7 KB bf16 temb [365][64]
    int*   tmp    = (int*)  (ws + 46600000);     // 400 KB
    ushort* rank  = (ushort*)(ws + 47000000);    //  2.0 MB (NE ushorts)
    int*   bsum   = (int*)  (ws + 49000000);     //  ~2 KB
    int*   bpref  = (int*)  (ws + 49010000);     //  ~2 KB

    prep_wtb_kernel<<<12, 256, 0, stream>>>(Wp, Wn, Wf, WTB);
    prep_tb_kernel<<<133, 256, 0, stream>>>(rela_embed, time_embed, relb, tembb);
    prep_tables_kernel<<<NL, 256, 0, stream>>>(rela_embed, W1, Trel, Tq);

    // --- counting sort by dst (rank captured in hist; scatter atomic-free) ---
    hipMemsetAsync(deg, 0, NN * sizeof(int), stream);
    hipMemsetAsync(out, 0, NOUT * sizeof(float), stream);  // zero tail for fused out
    hist_kernel<<<(NE + 255) / 256, 256, 0, stream>>>(dst_idx, deg, rank);
    scan1_kernel<<<NBLK1, 256, 0, stream>>>(deg, tmp, bsum);
    scan2_kernel<<<1, 512, 0, stream>>>(bsum, bpref);
    scan3_kernel<<<NBLK1, 256, 0, stream>>>(deg, tmp, bpref, off);
    sort_scatter_kernel<<<(NE + 255) / 256, 256, 0, stream>>>(
        dst_idx, src_idx, rel_idx, rel_time, batch_idx, query_rel,
        off, rank, Trel, Tq, W2, meta, score);

    // --- layers: L0 -> hid0/projA ; L1 hid0,projA -> hid1/projB ;
    //             L2 hid1,projB -> out (fused Wc dot) ---
    int grid = NBLK2;
    int sgrid = (NE + 255) / 256;
    {
        reduce_transform_kernel<true, true, false><<<grid, 256, 0, stream>>>(
            hid1, relb, tembb, score, meta, off,
            WTB, W1 + (size_t)1 * AD * 192, hid0, projA,
            nullptr, nullptr, nullptr);
    }
    {
        score_kernel<<<sgrid, 256, 0, stream>>>(
            projA, Trel + (size_t)1 * NRL * 8, Tq + (size_t)1 * NRL * 8,
            W2 + 1 * AD, meta, score);
        reduce_transform_kernel<false, true, false><<<grid, 256, 0, stream>>>(
            hid0, relb + (size_t)1 * NRL * HD, tembb, score, meta, off,
            WTB, W1 + (size_t)2 * AD * 192, hid1, projB,
            nullptr, nullptr, nullptr);
    }
    {
        score_kernel<<<sgrid, 256, 0, stream>>>(
            projB, Trel + (size_t)2 * NRL * 8, Tq + (size_t)2 * NRL * 8,
            W2 + 2 * AD, meta, score);
        reduce_transform_kernel<false, false, true><<<grid, 256, 0, stream>>>(
            hid1, relb + (size_t)2 * NRL * HD, tembb, score, meta, off,
            WTB, nullptr, nullptr, nullptr,
            Wc, bc, out);
    }
}